// Round 1
// 430.571 us; speedup vs baseline: 1.0068x; 1.0068x over previous
//
#include <hip/hip_runtime.h>

#define TABLE_SIZE 4096
#define BLOCK 256

// clang ext_vector type so __builtin_nontemporal_load/store accept it
// (HIP's float4 is a class type; the builtin needs a scalar/vector type).
typedef float f32x4 __attribute__((ext_vector_type(4)));

__device__ __forceinline__ float secgelu1(float xv, const float* __restrict__ t)
{
    // X = round-half-even(x * 2^16): rintf in RN mode == np.round
    float X = rintf(xv * 65536.0f);
    // y = floor(X / 64): exact (X integral, /64 is an exponent shift)
    float y = floorf(X * 0.015625f);
    bool  d = (y >= 0.0f);
    float a = fminf(fabsf(y), (float)(TABLE_SIZE - 1)); // a = |y| clamped
    return (d ? xv : 0.0f) - t[(int)a];
}

__global__ __launch_bounds__(BLOCK) void secgelu_kernel(
    const float* __restrict__ x, const float* __restrict__ table,
    float* __restrict__ out, int n4, int n)
{
    __shared__ float lds_table[TABLE_SIZE];
    // Stage the 16 KB table into LDS (coalesced, 16 iters of 256 threads).
    // Table reads go through L2 normally — it's the one thing we WANT cached.
    #pragma unroll
    for (int i = threadIdx.x; i < TABLE_SIZE; i += BLOCK)
        lds_table[i] = table[i];
    __syncthreads();

    const f32x4* __restrict__ x4 = (const f32x4*)x;
    f32x4* __restrict__ o4 = (f32x4*)out;

    const int stride = gridDim.x * BLOCK;
    int idx = blockIdx.x * BLOCK + threadIdx.x;

    // Main loop, 2x unrolled: two 1-KiB/wave nontemporal loads in flight
    // before any compute; nontemporal stores keep the 268 MB output stream
    // from cycling through L2/L3 (zero reuse — pure streaming).
    for (; idx + stride < n4; idx += 2 * stride) {
        f32x4 v0 = __builtin_nontemporal_load(&x4[idx]);
        f32x4 v1 = __builtin_nontemporal_load(&x4[idx + stride]);
        f32x4 r0, r1;
        #pragma unroll
        for (int k = 0; k < 4; ++k) r0[k] = secgelu1(v0[k], lds_table);
        #pragma unroll
        for (int k = 0; k < 4; ++k) r1[k] = secgelu1(v1[k], lds_table);
        __builtin_nontemporal_store(r0, &o4[idx]);
        __builtin_nontemporal_store(r1, &o4[idx + stride]);
    }
    // Remainder (runs only if n4 % (2*stride) leaves a single-stride chunk).
    for (; idx < n4; idx += stride) {
        f32x4 v = __builtin_nontemporal_load(&x4[idx]);
        f32x4 r;
        #pragma unroll
        for (int k = 0; k < 4; ++k) r[k] = secgelu1(v[k], lds_table);
        __builtin_nontemporal_store(r, &o4[idx]);
    }

    // Tail (n not divisible by 4) — dead for n = 4*4096*4096, kept for safety.
    int t0 = n4 * 4 + (int)(blockIdx.x * BLOCK + threadIdx.x);
    if (blockIdx.x == 0 && t0 < n) {
        out[t0] = secgelu1(x[t0], lds_table);
    }
}

extern "C" void kernel_launch(void* const* d_in, const int* in_sizes, int n_in,
                              void* d_out, int out_size, void* d_ws, size_t ws_size,
                              hipStream_t stream) {
    const float* x     = (const float*)d_in[0];
    const float* table = (const float*)d_in[1];
    float* out = (float*)d_out;
    int n  = in_sizes[0];
    int n4 = n / 4;

    // 8 blocks/CU * 256 CUs = 2048 blocks -> 32 waves/CU, full occupancy;
    // each thread handles exactly 32 float4s (16 unroll-2 iterations).
    int blocks = 2048;
    secgelu_kernel<<<blocks, BLOCK, 0, stream>>>(x, table, out, n4, n);
}